// Round 6
// baseline (373.379 us; speedup 1.0000x reference)
//
#include <hip/hip_runtime.h>
#include <stdint.h>

// Problem constants (reference: N=2048, M=100000, D=128, K=5)
#define N_Q 2048
#define M_B 100000
#define D_DIM 128
#define KNN 5
#define SLABS_TOTAL 1563            // ceil(M/64)
#define M_PAD (SLABS_TOTAL * 64)    // 100032
#define CHUNKS 128                  // R14: 2x finer chunks -> grid 1024 = 4 blk/CU
#define SPC 13                      // slabs per chunk; chunks 121..127 empty
#define CLS 16                      // col classes per chunk: col mod 16
#define FTOT (CHUNKS * CLS)         // 2048 rsm entries per row (phantoms = NEGF)
#define ROWBLOCKS 8
#define TROWS 256                   // 64 rows/wave (2x 32-row MFMA tiles)
#define BIGF 3.0e38f
#define NEGF -3.0e38f

// Accuracy (R9-R14, refines validated R6/R8 scheme): output = top-5 of per-
// (chunk x col-mod-16 class) bf16 acc maxima -- 1936 real candidate classes
// per row (121 non-empty chunks x 16; finer than R12's 1024 -> collision
// probability strictly lower). acc excludes the row-constant -x^2/2 (cannot
// change per-row argmax); k_scan reconstructs d2 = x2 - 2*acc with fp32 x2.
// Phantom classes (empty chunks / padded y-rows) carry NEGF, never selected.

typedef __attribute__((ext_vector_type(8))) short short8;      // MFMA A/B frag (8 bf16)
typedef __attribute__((ext_vector_type(4))) unsigned short ushort4v;
typedef __attribute__((ext_vector_type(8))) unsigned short ushort8v;
typedef __attribute__((ext_vector_type(16))) float f32x16;     // 32x32 MFMA C/D frag

static __device__ __forceinline__ unsigned short f2bf(float f) {
  unsigned int u = __builtin_bit_cast(unsigned int, f);
  u = (u + 0x7FFFu + ((u >> 16) & 1u)) >> 16;   // RNE
  return (unsigned short)u;
}

static __device__ __forceinline__ void gload_lds16(const void* g, void* l) {
  __builtin_amdgcn_global_load_lds((const __attribute__((address_space(1))) unsigned int*)g,
                                   (__attribute__((address_space(3))) unsigned int*)l, 16, 0, 0);
}
static __device__ __forceinline__ void gload_lds4(const void* g, void* l) {
  __builtin_amdgcn_global_load_lds((const __attribute__((address_space(1))) unsigned int*)g,
                                   (__attribute__((address_space(3))) unsigned int*)l, 4, 0, 0);
}

#define DPPADD(v, ctrl)                                                              \
  do {                                                                               \
    int _t = __builtin_amdgcn_update_dpp(0, __builtin_bit_cast(int, (v)), (ctrl),    \
                                         0xf, 0xf, false);                           \
    (v) = (v) + __builtin_bit_cast(float, _t);                                       \
  } while (0)

// ---------------------------------------------------------------------------
// K0: bank fp32 -> bf16 slab-tiled + ny2 = -0.5*|y|^2 (pads NEGF).
// Lane-contiguous flat reads; LDS-staged tile; coalesced 16B/lane writes.
// Tiled layout: slab s, unit u = kc*64 + j holds Y[s*64+j][kc*8 .. kc*8+8).
// ---------------------------------------------------------------------------
__global__ __launch_bounds__(256) void k_prep(const float* __restrict__ Y,
                                              unsigned short* __restrict__ ybf,
                                              float* __restrict__ ny2) {
  const int s = blockIdx.x;
  const int t = threadIdx.x;
  __shared__ __align__(16) unsigned short tile[8192];   // 16 KB bf16 slab
  __shared__ float redy[64 * 33];                       // padded
#pragma unroll
  for (int i = 0; i < 8; ++i) {
    const int u = i * 256 + t;                  // flat float4 index in 32KB slab
    const int rowl = u >> 5;                    // 0..63
    const int q = u & 31;                       // float4 within row
    const int rowg = s * 64 + rowl;
    const int rowc = (rowg < M_B) ? rowg : (M_B - 1);
    const float4 v = ((const float4*)Y)[(size_t)rowc * 32 + q];
    redy[rowl * 33 + q] = v.x * v.x + v.y * v.y + v.z * v.z + v.w * v.w;
    ushort4v o;
    o[0] = f2bf(v.x); o[1] = f2bf(v.y); o[2] = f2bf(v.z); o[3] = f2bf(v.w);
    *(ushort4v*)(tile + (size_t)(((q >> 1) * 64 + rowl) * 8 + (q & 1) * 4)) = o;
  }
  __syncthreads();
  {
    const int rowl = t >> 2;                    // quad per row
    const int k = t & 3;
    float ss = 0.f;
#pragma unroll
    for (int j = 0; j < 8; ++j) ss += redy[rowl * 33 + k * 8 + j];
    DPPADD(ss, 0xB1);                           // quad xor1
    DPPADD(ss, 0x4E);                           // quad xor2 -> quad sum
    const int rowg = s * 64 + rowl;
    if ((t & 3) == 0) ny2[(size_t)s * 64 + rowl] = (rowg < M_B) ? (-0.5f * ss) : NEGF;
  }
#pragma unroll
  for (int i = 0; i < 4; ++i) {                 // coalesced 16B/lane global writes
    const int u = i * 256 + t;
    *(ushort8v*)(ybf + ((size_t)s * 1024 + u) * 8) = *(const ushort8v*)(tile + u * 8);
  }
}

// ---------------------------------------------------------------------------
// Main: block = 256 rows x one chunk, 4 waves x 64 rows, 32x32x16 bf16 MFMA
// (2 rowtiles x 2 coltiles x 8 k-steps = 32 MFMA vs 16 ds_read_b128/slab).
// R14: OCCUPANCY. R5 post-mortem: wall 5088 cy/slab-iter vs pipe busies
// ~3100 cy (matrix 2066 + VALU 1000) -> ~2000 cy of pure waiting because at
// grid 512 each SIMD hosts only 2 waves (one per block) and both are often
// blocked on barrier/vmcnt/lgkmcnt simultaneously. Evidence: R2 (4 blk/CU,
// more LDS+VALU work) beat R3/R5 (2 blk/CU). Resources allow 4 waves/SIMD
// (104 VGPR -> 4 waves/SIMD per m69; LDS 36.1KB -> 4 blk/CU): the cap was
// grid size. Fix: CHUNKS=128, SPC=13 -> grid 1024 = 4 blk/CU = 16 waves/CU.
// Same total MFMA/LDS work; 4 independent-block waves per SIMD cover sync
// jitter and dep latency. XCD: 128%8==0, chunk = bid%128 -> all 8 rowblocks
// of a chunk on one XCD; per-XCD working set 16 chunks x 208KB = 3.3MB < L2.
// Keeps R10's pipeline: double-buffered 2x16KB LDS, raw s_barrier + counted
// s_waitcnt vmcnt(4), whole-chunk ny2 preload; no setprio (m190).
// 32x32 MFMA layouts (verified m74/m101): A[m=lane&31][k=(lane>>5)*8+j],
// B[n=lane&31][k=(lane>>5)*8+j], C/D col=lane&31, row=(reg&3)+8*(reg>>2)
// +4*(lane>>5). Epilogue merges col classes mod-32 -> mod-16 via
// shfl_xor(.,16) (lane^16 has same rows, same class&15, other col half).
// ---------------------------------------------------------------------------
__global__ __launch_bounds__(256, 4) void k_main(const float* __restrict__ X,
                                                 const unsigned short* __restrict__ ybf,
                                                 const float* __restrict__ ny2,
                                                 float* __restrict__ rsm) {
  __shared__ __align__(16) char smem[36096];
  unsigned short* ys = (unsigned short*)smem;        // 32768: two 16KB bf16 slab bufs
  float* ny2s = (float*)(smem + 32768);              //  3328: whole chunk's ny2 (13x64)

  const int bid = blockIdx.x;
  const int chunk = bid % CHUNKS;                    // 0..127 (XCD-local)
  const int rowblock = bid / CHUNKS;                 // 0..7
  const int row0 = rowblock * TROWS;

  const int cs0 = chunk * SPC;
  int nslab = SLABS_TOTAL - cs0;                     // chunk 120: 3; chunks>=121: <=0
  if (nslab > SPC) nslab = SPC;
  if (nslab < 0) nslab = 0;

  const int t = threadIdx.x;
  const int wave = t >> 6;
  const int lane = t & 63;
  const int l31 = lane & 31;
  const int lq5 = lane >> 5;                         // 0/1

  // ---- A fragments resident in registers (bf16): 64 rows per wave ----
  // afrag[rt][ks]: A[m=l31][k = lq5*8 + j] for rowtile rt, k-step ks (K=16)
  short8 afrag[2][8];
#pragma unroll
  for (int rt = 0; rt < 2; ++rt)
#pragma unroll
    for (int ks = 0; ks < 8; ++ks) {
      const float* xr = X + (size_t)(row0 + wave * 64 + rt * 32 + l31) * D_DIM + ks * 16 + lq5 * 8;
      const float4 a = *(const float4*)xr;
      const float4 b = *(const float4*)(xr + 4);
      short8 f;
      f[0] = (short)f2bf(a.x); f[1] = (short)f2bf(a.y);
      f[2] = (short)f2bf(a.z); f[3] = (short)f2bf(a.w);
      f[4] = (short)f2bf(b.x); f[5] = (short)f2bf(b.y);
      f[6] = (short)f2bf(b.z); f[7] = (short)f2bf(b.w);
      afrag[rt][ks] = f;
    }

  // ---- one-time ny2 preload for the whole chunk (64 floats per slab) ----
  for (int j = wave; j < nslab; j += 4)
    gload_lds4(ny2 + (size_t)(cs0 + j) * 64 + lane, ny2s + (size_t)j * 64);
  __syncthreads();   // full drain: afrag loads + ny2 DMA; vmcnt==0 entering loop

  // persistent per-(row,class32) running max; class = l31 (merged to &15 at end)
  float prmax[2][16];
#pragma unroll
  for (int rt = 0; rt < 2; ++rt)
#pragma unroll
    for (int r = 0; r < 16; ++r) prmax[rt][r] = NEGF;

  // per-lane constant part of the B-frag LDS address (in shorts):
  // elem index = lq5*512 + l31*8  + ks*1024 + ct*256  (+ buf*8192)
  const int blane = lq5 * 512 + l31 * 8;

  // ---- prologue: stage slab 0 into buf 0 (4 gload_lds16 per thread) ----
  if (nslab > 0) {
    const unsigned short* src = ybf + (size_t)cs0 * 8192;
#pragma unroll
    for (int i = 0; i < 4; ++i) {
      const int ub = i * 256 + wave * 64;
      gload_lds16(src + (size_t)(ub + lane) * 8, ys + (size_t)ub * 8);
    }
  }

  for (int s = 0; s < nslab; ++s) {
    const unsigned short* yb = ys + (size_t)((s & 1) * 8192) + blane;
    if (s + 1 < nslab) {
      // issue next slab's stage into the other buffer (WAR-safe: last reader
      // of that buffer finished at the previous iteration's barrier2)
      const unsigned short* src = ybf + (size_t)(cs0 + s + 1) * 8192;
      unsigned short* dst = ys + (size_t)(((s + 1) & 1) * 8192);
#pragma unroll
      for (int i = 0; i < 4; ++i) {
        const int ub = i * 256 + wave * 64;
        gload_lds16(src + (size_t)(ub + lane) * 8, dst + (size_t)ub * 8);
      }
      // wait only for slab s's 4 loads (oldest); s+1's 4 stay in flight
      asm volatile("s_waitcnt vmcnt(4)" ::: "memory");
    } else {
      asm volatile("s_waitcnt vmcnt(0)" ::: "memory");
    }
    __builtin_amdgcn_s_barrier();   // all waves' slab-s DMA landed -> visible

    // -0.5*|y|^2 for this lane's two col classes (ct*32 + l31)
    const float y2c0 = ny2s[s * 64 + l31];
    const float y2c1 = ny2s[s * 64 + 32 + l31];

    f32x16 acc[2][2];                              // [rowtile][coltile]
#pragma unroll
    for (int rt = 0; rt < 2; ++rt)
#pragma unroll
      for (int r = 0; r < 16; ++r) {
        acc[rt][0][r] = y2c0;
        acc[rt][1][r] = y2c1;
      }

    // B fragments: all 16 b128 reads issued up front (compiler gates MFMA
    // with fine-grained lgkmcnt); addresses = yb + compile-time offsets
    short8 bfr[2][8];
#pragma unroll
    for (int ct = 0; ct < 2; ++ct)
#pragma unroll
      for (int ks = 0; ks < 8; ++ks)
        bfr[ct][ks] = *(const short8*)(yb + ks * 1024 + ct * 256);

#pragma unroll
    for (int ct = 0; ct < 2; ++ct)
#pragma unroll
      for (int rt = 0; rt < 2; ++rt)
#pragma unroll
        for (int ks = 0; ks < 8; ++ks)
          acc[rt][ct] = __builtin_amdgcn_mfma_f32_32x32x16_bf16(afrag[rt][ks], bfr[ct][ks],
                                                                acc[rt][ct], 0, 0, 0);

    // combine both coltiles into the persistent class max (v_max3)
#pragma unroll
    for (int rt = 0; rt < 2; ++rt)
#pragma unroll
      for (int r = 0; r < 16; ++r)
        prmax[rt][r] = fmaxf(prmax[rt][r], fmaxf(acc[rt][0][r], acc[rt][1][r]));

    __builtin_amdgcn_s_barrier();   // all waves done reading buf[s&1] before
                                    // iter s+1 issues stage(s+2) into it
  }

  // ---- epilogue: merge col classes mod32 -> mod16 across lane^16, write rsm.
  // lane and lane^16: same lq5 (same rows), same class&15, other col half.
#pragma unroll
  for (int rt = 0; rt < 2; ++rt)
#pragma unroll
    for (int r = 0; r < 16; ++r) {
      float v = prmax[rt][r];
      v = fmaxf(v, __shfl_xor(v, 16));
      if ((lane & 16) == 0) {
        const int lrow = wave * 64 + rt * 32 + (r & 3) + 8 * (r >> 2) + 4 * lq5;
        rsm[(size_t)(row0 + lrow) * FTOT + chunk * CLS + (lane & 15)] = v;
      }
    }
}

// ---------------------------------------------------------------------------
// K_scan: one wave per row. x2 = |x_row|^2 (fp32, wave reduce); top-5 largest
// acc over the row's 2048 class maxima (coalesced), per-lane sorted-5 + 5-round
// wave-max merge; d2 = x2 - 2*acc; sqrt/mean/normalize -> out[row].
// ---------------------------------------------------------------------------
__global__ __launch_bounds__(256) void k_scan(const float* __restrict__ rsm,
                                              const float* __restrict__ X,
                                              const float* __restrict__ minp,
                                              const float* __restrict__ maxp,
                                              float* __restrict__ out) {
  const int wave = threadIdx.x >> 6;
  const int lane = threadIdx.x & 63;
  const int row = blockIdx.x * 4 + wave;
  const float* rp = rsm + (size_t)row * FTOT;

  // x2: 2 floats per lane, butterfly sum
  float x2;
  {
    const float a = X[(size_t)row * D_DIM + lane];
    const float b = X[(size_t)row * D_DIM + 64 + lane];
    x2 = a * a + b * b;
#pragma unroll
    for (int off = 1; off < 64; off <<= 1) x2 += __shfl_xor(x2, off);
  }

  float t0 = NEGF, t1 = NEGF, t2 = NEGF, t3 = NEGF, t4 = NEGF;  // descending
  for (int i = lane; i < FTOT; i += 64) {
    const float v = rp[i];
    if (v > t4) {
      float m = v;
      float n3 = fminf(t3, m); m = fmaxf(t3, m);
      float n2 = fminf(t2, m); m = fmaxf(t2, m);
      float n1 = fminf(t1, m); m = fmaxf(t1, m);
      float n0 = fminf(t0, m); m = fmaxf(t0, m);
      t0 = m; t1 = n0; t2 = n1; t3 = n2; t4 = n3;
    }
  }

  int k = 0;
  float sum = 0.f;
#pragma unroll
  for (int r = 0; r < KNN; ++r) {
    float head = (k == 0) ? t0 : (k == 1) ? t1 : (k == 2) ? t2 : (k == 3) ? t3
               : (k == 4) ? t4 : NEGF;
    float m = head;
#pragma unroll
    for (int off = 1; off < 64; off <<= 1) m = fmaxf(m, __shfl_xor(m, off));
    const unsigned long long mask = __ballot(head == m);
    const int first = __ffsll(mask) - 1;
    if (lane == first) ++k;                      // consume exactly one holder
    sum += sqrtf(fmaxf(x2 - 2.f * m, 0.f));      // d = sqrt(x2 - 2*acc)
  }
  if (lane == 0) {
    const float mn = minp[0], mx = maxp[0];
    out[row] = (sum * (1.0f / KNN) - mn) / (mx - mn);
  }
}

extern "C" void kernel_launch(void* const* d_in, const int* in_sizes, int n_in,
                              void* d_out, int out_size, void* d_ws, size_t ws_size,
                              hipStream_t stream) {
  const float* X = (const float*)d_in[0];
  const float* Y = (const float*)d_in[1];
  const float* minp = (const float*)d_in[2];
  const float* maxp = (const float*)d_in[3];
  float* out = (float*)d_out;

  char* ws = (char*)d_ws;
  size_t off = 0;
  unsigned short* ybf = (unsigned short*)(ws + off); off += (size_t)M_PAD * D_DIM * 2;  // 25.6 MB
  float* ny2 = (float*)(ws + off);                   off += (size_t)M_PAD * 4;          // 400 KB
  float* rsm = (float*)(ws + off);                   off += (size_t)N_Q * FTOT * 4;     // 16.8 MB
  // total ~42.8 MB

  k_prep<<<dim3(SLABS_TOTAL), dim3(256), 0, stream>>>(Y, ybf, ny2);
  k_main<<<dim3(ROWBLOCKS * CHUNKS), dim3(256), 0, stream>>>(X, ybf, ny2, rsm);
  k_scan<<<dim3(N_Q / 4), dim3(256), 0, stream>>>(rsm, X, minp, maxp, out);
}

// Round 7
// 184.658 us; speedup vs baseline: 2.0220x; 2.0220x over previous
//
#include <hip/hip_runtime.h>
#include <stdint.h>

// Problem constants (reference: N=2048, M=100000, D=128, K=5)
#define N_Q 2048
#define M_B 100000
#define D_DIM 128
#define KNN 5
#define SLABS_TOTAL 1563            // ceil(M/64)
#define M_PAD (SLABS_TOTAL * 64)    // 100032
#define CHUNKS 96                   // R15: grid 768 = 3 blk/CU (96%8==0 for XCD)
#define SPC 17                      // slabs per chunk; chunk 91: 16; 92..95 empty
#define CLS 16                      // col classes per chunk: col mod 16
#define FTOT (CHUNKS * CLS)         // 1536 rsm entries per row (phantoms = NEGF)
#define ROWBLOCKS 8
#define TROWS 256                   // 64 rows/wave (2x 32-row MFMA tiles)
#define BIGF 3.0e38f
#define NEGF -3.0e38f

// Accuracy (R9-R15, refines validated R6/R8 scheme): output = top-5 of per-
// (chunk x col-mod-16 class) bf16 acc maxima -- 1472 real candidate classes
// per row (92 non-empty chunks x 16). acc excludes the row-constant -x^2/2
// (cannot change per-row argmax); k_scan reconstructs d2 = x2 - 2*acc with
// fp32 x2. Phantom classes (empty chunks / padded y-rows) carry NEGF.
// Same per-class candidate set + fmax order as R12/R13 (bit-identical).

typedef __attribute__((ext_vector_type(8))) short short8;      // MFMA A/B frag (8 bf16)
typedef __attribute__((ext_vector_type(4))) unsigned short ushort4v;
typedef __attribute__((ext_vector_type(8))) unsigned short ushort8v;
typedef __attribute__((ext_vector_type(16))) float f32x16;     // 32x32 MFMA C/D frag

static __device__ __forceinline__ unsigned short f2bf(float f) {
  unsigned int u = __builtin_bit_cast(unsigned int, f);
  u = (u + 0x7FFFu + ((u >> 16) & 1u)) >> 16;   // RNE
  return (unsigned short)u;
}

static __device__ __forceinline__ void gload_lds16(const void* g, void* l) {
  __builtin_amdgcn_global_load_lds((const __attribute__((address_space(1))) unsigned int*)g,
                                   (__attribute__((address_space(3))) unsigned int*)l, 16, 0, 0);
}
static __device__ __forceinline__ void gload_lds4(const void* g, void* l) {
  __builtin_amdgcn_global_load_lds((const __attribute__((address_space(1))) unsigned int*)g,
                                   (__attribute__((address_space(3))) unsigned int*)l, 4, 0, 0);
}

#define DPPADD(v, ctrl)                                                              \
  do {                                                                               \
    int _t = __builtin_amdgcn_update_dpp(0, __builtin_bit_cast(int, (v)), (ctrl),    \
                                         0xf, 0xf, false);                           \
    (v) = (v) + __builtin_bit_cast(float, _t);                                       \
  } while (0)

// ---------------------------------------------------------------------------
// K0: bank fp32 -> bf16 slab-tiled + ny2 = -0.5*|y|^2 (pads NEGF).
// Lane-contiguous flat reads; LDS-staged tile; coalesced 16B/lane writes.
// Tiled layout: slab s, unit u = kc*64 + j holds Y[s*64+j][kc*8 .. kc*8+8).
// ---------------------------------------------------------------------------
__global__ __launch_bounds__(256) void k_prep(const float* __restrict__ Y,
                                              unsigned short* __restrict__ ybf,
                                              float* __restrict__ ny2) {
  const int s = blockIdx.x;
  const int t = threadIdx.x;
  __shared__ __align__(16) unsigned short tile[8192];   // 16 KB bf16 slab
  __shared__ float redy[64 * 33];                       // padded
#pragma unroll
  for (int i = 0; i < 8; ++i) {
    const int u = i * 256 + t;                  // flat float4 index in 32KB slab
    const int rowl = u >> 5;                    // 0..63
    const int q = u & 31;                       // float4 within row
    const int rowg = s * 64 + rowl;
    const int rowc = (rowg < M_B) ? rowg : (M_B - 1);
    const float4 v = ((const float4*)Y)[(size_t)rowc * 32 + q];
    redy[rowl * 33 + q] = v.x * v.x + v.y * v.y + v.z * v.z + v.w * v.w;
    ushort4v o;
    o[0] = f2bf(v.x); o[1] = f2bf(v.y); o[2] = f2bf(v.z); o[3] = f2bf(v.w);
    *(ushort4v*)(tile + (size_t)(((q >> 1) * 64 + rowl) * 8 + (q & 1) * 4)) = o;
  }
  __syncthreads();
  {
    const int rowl = t >> 2;                    // quad per row
    const int k = t & 3;
    float ss = 0.f;
#pragma unroll
    for (int j = 0; j < 8; ++j) ss += redy[rowl * 33 + k * 8 + j];
    DPPADD(ss, 0xB1);                           // quad xor1
    DPPADD(ss, 0x4E);                           // quad xor2 -> quad sum
    const int rowg = s * 64 + rowl;
    if ((t & 3) == 0) ny2[(size_t)s * 64 + rowl] = (rowg < M_B) ? (-0.5f * ss) : NEGF;
  }
#pragma unroll
  for (int i = 0; i < 4; ++i) {                 // coalesced 16B/lane global writes
    const int u = i * 256 + t;
    *(ushort8v*)(ybf + ((size_t)s * 1024 + u) * 8) = *(const ushort8v*)(tile + u * 8);
  }
}

// ---------------------------------------------------------------------------
// Main: block = 256 rows x one chunk, 4 waves x 64 rows, 32x32x16 bf16 MFMA.
// R15: 3 blocks/CU WITHOUT spilling. R6 post-mortem: launch_bounds(256,4)
// capped the unified reg file at 128/wave but the kernel's true footprint is
// ~168 (VGPR_Count excludes AGPRs; acc f32x16 arrays live in AGPRs) -> acc
// spilled to scratch (WRITE 8->460MB, FETCH 17->569MB, 55->270us). Fix:
// (a) CHUNKS=96 -> grid 768 = exactly 3 blk/CU = 3 waves/SIMD (R5 showed
// ~2000cy/slab pure waiting at 2 waves/SIMD; R2's 4-block config beat it
// despite 2x LDS work); (b) ct-OUTER loop: the two 32-col tiles are
// processed sequentially, so only acc[2] (32 regs) is live, not acc[2][2]
// (64) -> total ~142 regs < 170 = floor(512/3); launch_bounds(256,3).
// Same MFMA count (32/slab/wave), same 16 ds_read_b128/slab/wave, same
// candidate set + fmax order as R12/R13. XCD: 96%8==0, chunk = bid%96 ->
// all 8 rowblocks of a chunk on one XCD; 12 chunks x 272KB = 3.3MB < L2.
// Pipeline: double-buffered 2x16KB LDS, raw s_barrier + counted vmcnt(4)
// (slab s+1's 4 loads in flight across the barrier), whole-chunk ny2
// preload; no setprio (m190: negative on lockstep 2-phase).
// 32x32 MFMA layouts (verified m74/m101): A[m=lane&31][k=(lane>>5)*8+j],
// B[n=lane&31][k=(lane>>5)*8+j], C/D col=lane&31, row=(reg&3)+8*(reg>>2)
// +4*(lane>>5). Epilogue merges col classes mod-32 -> mod-16 via
// shfl_xor(.,16) (lane^16: same rows, same class&15, other col half).
// ---------------------------------------------------------------------------
__global__ __launch_bounds__(256, 3) void k_main(const float* __restrict__ X,
                                                 const unsigned short* __restrict__ ybf,
                                                 const float* __restrict__ ny2,
                                                 float* __restrict__ rsm) {
  __shared__ __align__(16) char smem[37120];
  unsigned short* ys = (unsigned short*)smem;        // 32768: two 16KB bf16 slab bufs
  float* ny2s = (float*)(smem + 32768);              //  4352: whole chunk's ny2 (17x64)

  const int bid = blockIdx.x;
  const int chunk = bid % CHUNKS;                    // 0..95 (XCD-local)
  const int rowblock = bid / CHUNKS;                 // 0..7
  const int row0 = rowblock * TROWS;

  const int cs0 = chunk * SPC;
  int nslab = SLABS_TOTAL - cs0;                     // chunk 91: 16; chunks>=92: <=0
  if (nslab > SPC) nslab = SPC;
  if (nslab < 0) nslab = 0;

  const int t = threadIdx.x;
  const int wave = t >> 6;
  const int lane = t & 63;
  const int l31 = lane & 31;
  const int lq5 = lane >> 5;                         // 0/1

  // ---- A fragments resident in registers (bf16): 64 rows per wave ----
  // afrag[rt][ks]: A[m=l31][k = lq5*8 + j] for rowtile rt, k-step ks (K=16)
  short8 afrag[2][8];
#pragma unroll
  for (int rt = 0; rt < 2; ++rt)
#pragma unroll
    for (int ks = 0; ks < 8; ++ks) {
      const float* xr = X + (size_t)(row0 + wave * 64 + rt * 32 + l31) * D_DIM + ks * 16 + lq5 * 8;
      const float4 a = *(const float4*)xr;
      const float4 b = *(const float4*)(xr + 4);
      short8 f;
      f[0] = (short)f2bf(a.x); f[1] = (short)f2bf(a.y);
      f[2] = (short)f2bf(a.z); f[3] = (short)f2bf(a.w);
      f[4] = (short)f2bf(b.x); f[5] = (short)f2bf(b.y);
      f[6] = (short)f2bf(b.z); f[7] = (short)f2bf(b.w);
      afrag[rt][ks] = f;
    }

  // ---- one-time ny2 preload for the whole chunk (64 floats per slab) ----
  for (int j = wave; j < nslab; j += 4)
    gload_lds4(ny2 + (size_t)(cs0 + j) * 64 + lane, ny2s + (size_t)j * 64);
  __syncthreads();   // full drain: afrag loads + ny2 DMA; vmcnt==0 entering loop

  // persistent per-(row,class32) running max; class = l31 (merged to &15 at end)
  float prmax[2][16];
#pragma unroll
  for (int rt = 0; rt < 2; ++rt)
#pragma unroll
    for (int r = 0; r < 16; ++r) prmax[rt][r] = NEGF;

  // per-lane constant part of the B-frag LDS address (in shorts):
  // elem index = lq5*512 + l31*8  + ks*1024 + ct*256  (+ buf*8192)
  const int blane = lq5 * 512 + l31 * 8;

  // ---- prologue: stage slab 0 into buf 0 (4 gload_lds16 per thread) ----
  if (nslab > 0) {
    const unsigned short* src = ybf + (size_t)cs0 * 8192;
#pragma unroll
    for (int i = 0; i < 4; ++i) {
      const int ub = i * 256 + wave * 64;
      gload_lds16(src + (size_t)(ub + lane) * 8, ys + (size_t)ub * 8);
    }
  }

  for (int s = 0; s < nslab; ++s) {
    const unsigned short* yb = ys + (size_t)((s & 1) * 8192) + blane;
    if (s + 1 < nslab) {
      // issue next slab's stage into the other buffer (WAR-safe: last reader
      // of that buffer finished at the previous iteration's barrier2)
      const unsigned short* src = ybf + (size_t)(cs0 + s + 1) * 8192;
      unsigned short* dst = ys + (size_t)(((s + 1) & 1) * 8192);
#pragma unroll
      for (int i = 0; i < 4; ++i) {
        const int ub = i * 256 + wave * 64;
        gload_lds16(src + (size_t)(ub + lane) * 8, dst + (size_t)ub * 8);
      }
      // wait only for slab s's 4 loads (oldest); s+1's 4 stay in flight
      asm volatile("s_waitcnt vmcnt(4)" ::: "memory");
    } else {
      asm volatile("s_waitcnt vmcnt(0)" ::: "memory");
    }
    __builtin_amdgcn_s_barrier();   // all waves' slab-s DMA landed -> visible

    // -0.5*|y|^2 for this lane's two col classes (ct*32 + l31)
    const float y2c0 = ny2s[s * 64 + l31];
    const float y2c1 = ny2s[s * 64 + 32 + l31];

    // ct-OUTER: one coltile's acc pair live at a time (32 regs, not 64)
#pragma unroll
    for (int ct = 0; ct < 2; ++ct) {
      f32x16 acc0, acc1;                           // [rowtile 0/1]
      const float yc = (ct == 0) ? y2c0 : y2c1;
#pragma unroll
      for (int r = 0; r < 16; ++r) { acc0[r] = yc; acc1[r] = yc; }

#pragma unroll
      for (int ks = 0; ks < 8; ++ks) {
        const short8 bfr = *(const short8*)(yb + ks * 1024 + ct * 256);
        acc0 = __builtin_amdgcn_mfma_f32_32x32x16_bf16(afrag[0][ks], bfr, acc0, 0, 0, 0);
        acc1 = __builtin_amdgcn_mfma_f32_32x32x16_bf16(afrag[1][ks], bfr, acc1, 0, 0, 0);
      }

#pragma unroll
      for (int r = 0; r < 16; ++r) {
        prmax[0][r] = fmaxf(prmax[0][r], acc0[r]);
        prmax[1][r] = fmaxf(prmax[1][r], acc1[r]);
      }
    }

    __builtin_amdgcn_s_barrier();   // all waves done reading buf[s&1] before
                                    // iter s+1 issues stage(s+2) into it
  }

  // ---- epilogue: merge col classes mod32 -> mod16 across lane^16, write rsm.
  // lane and lane^16: same lq5 (same rows), same class&15, other col half.
#pragma unroll
  for (int rt = 0; rt < 2; ++rt)
#pragma unroll
    for (int r = 0; r < 16; ++r) {
      float v = prmax[rt][r];
      v = fmaxf(v, __shfl_xor(v, 16));
      if ((lane & 16) == 0) {
        const int lrow = wave * 64 + rt * 32 + (r & 3) + 8 * (r >> 2) + 4 * lq5;
        rsm[(size_t)(row0 + lrow) * FTOT + chunk * CLS + (lane & 15)] = v;
      }
    }
}

// ---------------------------------------------------------------------------
// K_scan: one wave per row. x2 = |x_row|^2 (fp32, wave reduce); top-5 largest
// acc over the row's 1536 class maxima (coalesced), per-lane sorted-5 + 5-round
// wave-max merge; d2 = x2 - 2*acc; sqrt/mean/normalize -> out[row].
// ---------------------------------------------------------------------------
__global__ __launch_bounds__(256) void k_scan(const float* __restrict__ rsm,
                                              const float* __restrict__ X,
                                              const float* __restrict__ minp,
                                              const float* __restrict__ maxp,
                                              float* __restrict__ out) {
  const int wave = threadIdx.x >> 6;
  const int lane = threadIdx.x & 63;
  const int row = blockIdx.x * 4 + wave;
  const float* rp = rsm + (size_t)row * FTOT;

  // x2: 2 floats per lane, butterfly sum
  float x2;
  {
    const float a = X[(size_t)row * D_DIM + lane];
    const float b = X[(size_t)row * D_DIM + 64 + lane];
    x2 = a * a + b * b;
#pragma unroll
    for (int off = 1; off < 64; off <<= 1) x2 += __shfl_xor(x2, off);
  }

  float t0 = NEGF, t1 = NEGF, t2 = NEGF, t3 = NEGF, t4 = NEGF;  // descending
  for (int i = lane; i < FTOT; i += 64) {
    const float v = rp[i];
    if (v > t4) {
      float m = v;
      float n3 = fminf(t3, m); m = fmaxf(t3, m);
      float n2 = fminf(t2, m); m = fmaxf(t2, m);
      float n1 = fminf(t1, m); m = fmaxf(t1, m);
      float n0 = fminf(t0, m); m = fmaxf(t0, m);
      t0 = m; t1 = n0; t2 = n1; t3 = n2; t4 = n3;
    }
  }

  int k = 0;
  float sum = 0.f;
#pragma unroll
  for (int r = 0; r < KNN; ++r) {
    float head = (k == 0) ? t0 : (k == 1) ? t1 : (k == 2) ? t2 : (k == 3) ? t3
               : (k == 4) ? t4 : NEGF;
    float m = head;
#pragma unroll
    for (int off = 1; off < 64; off <<= 1) m = fmaxf(m, __shfl_xor(m, off));
    const unsigned long long mask = __ballot(head == m);
    const int first = __ffsll(mask) - 1;
    if (lane == first) ++k;                      // consume exactly one holder
    sum += sqrtf(fmaxf(x2 - 2.f * m, 0.f));      // d = sqrt(x2 - 2*acc)
  }
  if (lane == 0) {
    const float mn = minp[0], mx = maxp[0];
    out[row] = (sum * (1.0f / KNN) - mn) / (mx - mn);
  }
}

extern "C" void kernel_launch(void* const* d_in, const int* in_sizes, int n_in,
                              void* d_out, int out_size, void* d_ws, size_t ws_size,
                              hipStream_t stream) {
  const float* X = (const float*)d_in[0];
  const float* Y = (const float*)d_in[1];
  const float* minp = (const float*)d_in[2];
  const float* maxp = (const float*)d_in[3];
  float* out = (float*)d_out;

  char* ws = (char*)d_ws;
  size_t off = 0;
  unsigned short* ybf = (unsigned short*)(ws + off); off += (size_t)M_PAD * D_DIM * 2;  // 25.6 MB
  float* ny2 = (float*)(ws + off);                   off += (size_t)M_PAD * 4;          // 400 KB
  float* rsm = (float*)(ws + off);                   off += (size_t)N_Q * FTOT * 4;     // 12.6 MB
  // total ~38.6 MB

  k_prep<<<dim3(SLABS_TOTAL), dim3(256), 0, stream>>>(Y, ybf, ny2);
  k_main<<<dim3(ROWBLOCKS * CHUNKS), dim3(256), 0, stream>>>(X, ybf, ny2, rsm);
  k_scan<<<dim3(N_Q / 4), dim3(256), 0, stream>>>(rsm, X, minp, maxp, out);
}

// Round 8
// 150.129 us; speedup vs baseline: 2.4871x; 1.2300x over previous
//
#include <hip/hip_runtime.h>
#include <stdint.h>

// Problem constants (reference: N=2048, M=100000, D=128, K=5)
#define N_Q 2048
#define M_B 100000
#define D_DIM 128
#define KNN 5
#define SLABS_TOTAL 1563            // ceil(M/64)
#define M_PAD (SLABS_TOTAL * 64)    // 100032
#define CHUNKS 96                   // grid 768 = 3 blk/CU (96%8==0 for XCD)
#define SPC 17                      // slabs per chunk; chunk 91: 16; 92..95 empty
#define CLS 16                      // col classes per chunk: col mod 16
#define FTOT (CHUNKS * CLS)         // 1536 rsm entries per row (phantoms = NEGF)
#define ROWBLOCKS 8
#define TROWS 256                   // 64 rows/wave (4x 16-row MFMA tiles)
#define BIGF 3.0e38f
#define NEGF -3.0e38f

// Accuracy (R9-R16, refines validated R6/R8 scheme): output = top-5 of per-
// (chunk x col-mod-16 class) bf16 acc maxima -- 1472 real candidate classes
// per row (92 non-empty chunks x 16). acc excludes the row-constant -x^2/2
// (cannot change per-row argmax); k_scan reconstructs d2 = x2 - 2*acc with
// fp32 x2. Phantom classes (empty chunks / padded y-rows) carry NEGF.
// Same per-class candidate set as R10-R15; fmax order-insensitive.

typedef __attribute__((ext_vector_type(8))) short short8;      // MFMA A/B frag (8 bf16)
typedef __attribute__((ext_vector_type(4))) unsigned short ushort4v;
typedef __attribute__((ext_vector_type(8))) unsigned short ushort8v;
typedef __attribute__((ext_vector_type(4))) float f32x4;       // 16x16 MFMA C/D frag

static __device__ __forceinline__ unsigned short f2bf(float f) {
  unsigned int u = __builtin_bit_cast(unsigned int, f);
  u = (u + 0x7FFFu + ((u >> 16) & 1u)) >> 16;   // RNE
  return (unsigned short)u;
}

static __device__ __forceinline__ void gload_lds16(const void* g, void* l) {
  __builtin_amdgcn_global_load_lds((const __attribute__((address_space(1))) unsigned int*)g,
                                   (__attribute__((address_space(3))) unsigned int*)l, 16, 0, 0);
}
static __device__ __forceinline__ void gload_lds4(const void* g, void* l) {
  __builtin_amdgcn_global_load_lds((const __attribute__((address_space(1))) unsigned int*)g,
                                   (__attribute__((address_space(3))) unsigned int*)l, 4, 0, 0);
}

#define DPPADD(v, ctrl)                                                              \
  do {                                                                               \
    int _t = __builtin_amdgcn_update_dpp(0, __builtin_bit_cast(int, (v)), (ctrl),    \
                                         0xf, 0xf, false);                           \
    (v) = (v) + __builtin_bit_cast(float, _t);                                       \
  } while (0)

// ---------------------------------------------------------------------------
// K0: bank fp32 -> bf16 slab-tiled + ny2 = -0.5*|y|^2 (pads NEGF).
// Lane-contiguous flat reads; LDS-staged tile; coalesced 16B/lane writes.
// Tiled layout: slab s, unit u = kc*64 + j holds Y[s*64+j][kc*8 .. kc*8+8).
// ---------------------------------------------------------------------------
__global__ __launch_bounds__(256) void k_prep(const float* __restrict__ Y,
                                              unsigned short* __restrict__ ybf,
                                              float* __restrict__ ny2) {
  const int s = blockIdx.x;
  const int t = threadIdx.x;
  __shared__ __align__(16) unsigned short tile[8192];   // 16 KB bf16 slab
  __shared__ float redy[64 * 33];                       // padded
#pragma unroll
  for (int i = 0; i < 8; ++i) {
    const int u = i * 256 + t;                  // flat float4 index in 32KB slab
    const int rowl = u >> 5;                    // 0..63
    const int q = u & 31;                       // float4 within row
    const int rowg = s * 64 + rowl;
    const int rowc = (rowg < M_B) ? rowg : (M_B - 1);
    const float4 v = ((const float4*)Y)[(size_t)rowc * 32 + q];
    redy[rowl * 33 + q] = v.x * v.x + v.y * v.y + v.z * v.z + v.w * v.w;
    ushort4v o;
    o[0] = f2bf(v.x); o[1] = f2bf(v.y); o[2] = f2bf(v.z); o[3] = f2bf(v.w);
    *(ushort4v*)(tile + (size_t)(((q >> 1) * 64 + rowl) * 8 + (q & 1) * 4)) = o;
  }
  __syncthreads();
  {
    const int rowl = t >> 2;                    // quad per row
    const int k = t & 3;
    float ss = 0.f;
#pragma unroll
    for (int j = 0; j < 8; ++j) ss += redy[rowl * 33 + k * 8 + j];
    DPPADD(ss, 0xB1);                           // quad xor1
    DPPADD(ss, 0x4E);                           // quad xor2 -> quad sum
    const int rowg = s * 64 + rowl;
    if ((t & 3) == 0) ny2[(size_t)s * 64 + rowl] = (rowg < M_B) ? (-0.5f * ss) : NEGF;
  }
#pragma unroll
  for (int i = 0; i < 4; ++i) {                 // coalesced 16B/lane global writes
    const int u = i * 256 + t;
    *(ushort8v*)(ybf + ((size_t)s * 1024 + u) * 8) = *(const ushort8v*)(tile + u * 8);
  }
}

// ---------------------------------------------------------------------------
// Main: block = 256 rows x one chunk, 4 waves x 64 rows. R16: 16x16x32 bf16
// MFMA, rt=4 rowtiles, ct-OUTER (4 col passes) -- per pass only acc[4]
// (f32x4, 16 regs) + bfr[4] (16) live; prmax[4][4] (16); afrag[4][4] (64);
// live-set ~127 << 168-reg cap at launch_bounds(256,3). R7 post-mortem: the
// 32x32 variant's f32x16 accs left no margin -> ~4 regs spilled per slab
// (WRITE 67MB). R5/R2 pipe accounting: 64 rows/wave puts LDS at ~32%, matrix
// ~51% of wall -- needs >=3 blk/CU (12 waves/CU) to overlap; R5's 2 blk/CU
// summed to 87% (serial/latency-bound). Grid 768 = 3 blk/CU exactly.
// Same 16 ds_read_b128 + 64 MFMA per slab/wave (each b128 read once; 4 per
// ct-pass). 16x16 C/D layout: class = lm directly -> no lane^16 merge.
// XCD: 96%8==0, chunk = bid%96 -> all 8 rowblocks on one XCD; 12 chunks x
// 272KB = 3.3MB < L2. Pipeline: double-buffered 2x16KB LDS, raw s_barrier +
// counted vmcnt(4), whole-chunk ny2 preload; no setprio (m190).
// MFMA layouts (verified m89/m91): A[m=lane&15][k=(lane>>4)*8+j],
// B[n=lane&15][k=(lane>>4)*8+j], C/D col=lane&15 row=(lane>>4)*4+reg.
// ---------------------------------------------------------------------------
__global__ __launch_bounds__(256, 3) void k_main(const float* __restrict__ X,
                                                 const unsigned short* __restrict__ ybf,
                                                 const float* __restrict__ ny2,
                                                 float* __restrict__ rsm) {
  __shared__ __align__(16) char smem[37120];
  unsigned short* ys = (unsigned short*)smem;        // 32768: two 16KB bf16 slab bufs
  float* ny2s = (float*)(smem + 32768);              //  4352: whole chunk's ny2 (17x64)

  const int bid = blockIdx.x;
  const int chunk = bid % CHUNKS;                    // 0..95 (XCD-local)
  const int rowblock = bid / CHUNKS;                 // 0..7
  const int row0 = rowblock * TROWS;

  const int cs0 = chunk * SPC;
  int nslab = SLABS_TOTAL - cs0;                     // chunk 91: 16; chunks>=92: <=0
  if (nslab > SPC) nslab = SPC;
  if (nslab < 0) nslab = 0;

  const int t = threadIdx.x;
  const int wave = t >> 6;
  const int lane = t & 63;
  const int lm = lane & 15;
  const int lq = lane >> 4;                          // 0..3

  // ---- A fragments resident in registers (bf16): 64 rows per wave ----
  // afrag[rt][ks]: A[m=lm][k = lq*8 + j] for rowtile rt, k-step ks (K=32)
  short8 afrag[4][4];
#pragma unroll
  for (int rt = 0; rt < 4; ++rt)
#pragma unroll
    for (int ks = 0; ks < 4; ++ks) {
      const float* xr = X + (size_t)(row0 + wave * 64 + rt * 16 + lm) * D_DIM + ks * 32 + lq * 8;
      const float4 a = *(const float4*)xr;
      const float4 b = *(const float4*)(xr + 4);
      short8 f;
      f[0] = (short)f2bf(a.x); f[1] = (short)f2bf(a.y);
      f[2] = (short)f2bf(a.z); f[3] = (short)f2bf(a.w);
      f[4] = (short)f2bf(b.x); f[5] = (short)f2bf(b.y);
      f[6] = (short)f2bf(b.z); f[7] = (short)f2bf(b.w);
      afrag[rt][ks] = f;
    }

  // ---- one-time ny2 preload for the whole chunk (64 floats per slab) ----
  for (int j = wave; j < nslab; j += 4)
    gload_lds4(ny2 + (size_t)(cs0 + j) * 64 + lane, ny2s + (size_t)j * 64);
  __syncthreads();   // full drain: afrag loads + ny2 DMA; vmcnt==0 entering loop

  // persistent per-(row,class) running max: lane holds class lm, rows (rt,rr)
  float prmax[4][4];
#pragma unroll
  for (int rt = 0; rt < 4; ++rt)
#pragma unroll
    for (int rr = 0; rr < 4; ++rr) prmax[rt][rr] = NEGF;

  // ---- prologue: stage slab 0 into buf 0 (4 gload_lds16 per thread) ----
  if (nslab > 0) {
    const unsigned short* src = ybf + (size_t)cs0 * 8192;
#pragma unroll
    for (int i = 0; i < 4; ++i) {
      const int ub = i * 256 + wave * 64;
      gload_lds16(src + (size_t)(ub + lane) * 8, ys + (size_t)ub * 8);
    }
  }

  for (int s = 0; s < nslab; ++s) {
    const unsigned short* yb = ys + (size_t)((s & 1) * 8192);
    if (s + 1 < nslab) {
      // issue next slab's stage into the other buffer (WAR-safe: last reader
      // of that buffer finished at the previous iteration's barrier2)
      const unsigned short* src = ybf + (size_t)(cs0 + s + 1) * 8192;
      unsigned short* dst = ys + (size_t)(((s + 1) & 1) * 8192);
#pragma unroll
      for (int i = 0; i < 4; ++i) {
        const int ub = i * 256 + wave * 64;
        gload_lds16(src + (size_t)(ub + lane) * 8, dst + (size_t)ub * 8);
      }
      // wait only for slab s's 4 loads (oldest); s+1's 4 stay in flight
      asm volatile("s_waitcnt vmcnt(4)" ::: "memory");
    } else {
      asm volatile("s_waitcnt vmcnt(0)" ::: "memory");
    }
    __builtin_amdgcn_s_barrier();   // all waves' slab-s DMA landed -> visible

    // ct-OUTER: one coltile at a time -> acc live-set is only 16 regs
#pragma unroll
    for (int ct = 0; ct < 4; ++ct) {
      const float yc = ny2s[s * 64 + ct * 16 + lm];  // -0.5*|y|^2, col ct*16+lm

      short8 bfr[4];
#pragma unroll
      for (int ks = 0; ks < 4; ++ks)
        bfr[ks] = *(const short8*)(yb + (size_t)(((ks * 4 + lq) * 64 + ct * 16 + lm)) * 8);

      f32x4 acc[4];                                  // [rowtile]
#pragma unroll
      for (int rt = 0; rt < 4; ++rt)
#pragma unroll
        for (int rr = 0; rr < 4; ++rr) acc[rt][rr] = yc;

#pragma unroll
      for (int ks = 0; ks < 4; ++ks)
#pragma unroll
        for (int rt = 0; rt < 4; ++rt)
          acc[rt] = __builtin_amdgcn_mfma_f32_16x16x32_bf16(afrag[rt][ks], bfr[ks],
                                                            acc[rt], 0, 0, 0);

#pragma unroll
      for (int rt = 0; rt < 4; ++rt)
#pragma unroll
        for (int rr = 0; rr < 4; ++rr)
          prmax[rt][rr] = fmaxf(prmax[rt][rr], acc[rt][rr]);
    }

    __builtin_amdgcn_s_barrier();   // all waves done reading buf[s&1] before
                                    // iter s+1 issues stage(s+2) into it
  }

  // ---- rsm write, row-major: rsm[row][chunk*CLS + lm], all 64 lanes ----
#pragma unroll
  for (int rt = 0; rt < 4; ++rt)
#pragma unroll
    for (int rr = 0; rr < 4; ++rr) {
      const int lrow = wave * 64 + rt * 16 + lq * 4 + rr;
      rsm[(size_t)(row0 + lrow) * FTOT + chunk * CLS + lm] = prmax[rt][rr];
    }
}

// ---------------------------------------------------------------------------
// K_scan: one wave per row. x2 = |x_row|^2 (fp32, wave reduce); top-5 largest
// acc over the row's 1536 class maxima (coalesced), per-lane sorted-5 + 5-round
// wave-max merge; d2 = x2 - 2*acc; sqrt/mean/normalize -> out[row].
// ---------------------------------------------------------------------------
__global__ __launch_bounds__(256) void k_scan(const float* __restrict__ rsm,
                                              const float* __restrict__ X,
                                              const float* __restrict__ minp,
                                              const float* __restrict__ maxp,
                                              float* __restrict__ out) {
  const int wave = threadIdx.x >> 6;
  const int lane = threadIdx.x & 63;
  const int row = blockIdx.x * 4 + wave;
  const float* rp = rsm + (size_t)row * FTOT;

  // x2: 2 floats per lane, butterfly sum
  float x2;
  {
    const float a = X[(size_t)row * D_DIM + lane];
    const float b = X[(size_t)row * D_DIM + 64 + lane];
    x2 = a * a + b * b;
#pragma unroll
    for (int off = 1; off < 64; off <<= 1) x2 += __shfl_xor(x2, off);
  }

  float t0 = NEGF, t1 = NEGF, t2 = NEGF, t3 = NEGF, t4 = NEGF;  // descending
  for (int i = lane; i < FTOT; i += 64) {
    const float v = rp[i];
    if (v > t4) {
      float m = v;
      float n3 = fminf(t3, m); m = fmaxf(t3, m);
      float n2 = fminf(t2, m); m = fmaxf(t2, m);
      float n1 = fminf(t1, m); m = fmaxf(t1, m);
      float n0 = fminf(t0, m); m = fmaxf(t0, m);
      t0 = m; t1 = n0; t2 = n1; t3 = n2; t4 = n3;
    }
  }

  int k = 0;
  float sum = 0.f;
#pragma unroll
  for (int r = 0; r < KNN; ++r) {
    float head = (k == 0) ? t0 : (k == 1) ? t1 : (k == 2) ? t2 : (k == 3) ? t3
               : (k == 4) ? t4 : NEGF;
    float m = head;
#pragma unroll
    for (int off = 1; off < 64; off <<= 1) m = fmaxf(m, __shfl_xor(m, off));
    const unsigned long long mask = __ballot(head == m);
    const int first = __ffsll(mask) - 1;
    if (lane == first) ++k;                      // consume exactly one holder
    sum += sqrtf(fmaxf(x2 - 2.f * m, 0.f));      // d = sqrt(x2 - 2*acc)
  }
  if (lane == 0) {
    const float mn = minp[0], mx = maxp[0];
    out[row] = (sum * (1.0f / KNN) - mn) / (mx - mn);
  }
}

extern "C" void kernel_launch(void* const* d_in, const int* in_sizes, int n_in,
                              void* d_out, int out_size, void* d_ws, size_t ws_size,
                              hipStream_t stream) {
  const float* X = (const float*)d_in[0];
  const float* Y = (const float*)d_in[1];
  const float* minp = (const float*)d_in[2];
  const float* maxp = (const float*)d_in[3];
  float* out = (float*)d_out;

  char* ws = (char*)d_ws;
  size_t off = 0;
  unsigned short* ybf = (unsigned short*)(ws + off); off += (size_t)M_PAD * D_DIM * 2;  // 25.6 MB
  float* ny2 = (float*)(ws + off);                   off += (size_t)M_PAD * 4;          // 400 KB
  float* rsm = (float*)(ws + off);                   off += (size_t)N_Q * FTOT * 4;     // 12.6 MB
  // total ~38.6 MB

  k_prep<<<dim3(SLABS_TOTAL), dim3(256), 0, stream>>>(Y, ybf, ny2);
  k_main<<<dim3(ROWBLOCKS * CHUNKS), dim3(256), 0, stream>>>(X, ybf, ny2, rsm);
  k_scan<<<dim3(N_Q / 4), dim3(256), 0, stream>>>(rsm, X, minp, maxp, out);
}

// Round 9
// 148.912 us; speedup vs baseline: 2.5074x; 1.0082x over previous
//
#include <hip/hip_runtime.h>
#include <stdint.h>

// Problem constants (reference: N=2048, M=100000, D=128, K=5)
#define N_Q 2048
#define M_B 100000
#define D_DIM 128
#define KNN 5
#define SLABS_TOTAL 1563            // ceil(M/64)
#define M_PAD (SLABS_TOTAL * 64)    // 100032
#define CHUNKS 96                   // grid 768 = 3 blk/CU (96%8==0 for XCD)
#define SPC 17                      // slabs per chunk; chunk 91: 16; 92..95 empty
#define CLS 16                      // col classes per chunk: col mod 16
#define FTOT (CHUNKS * CLS)         // 1536 rsm entries per row (phantoms = NEGF)
#define ROWBLOCKS 8
#define TROWS 256                   // 64 rows/wave (4x 16-row MFMA tiles)
#define BIGF 3.0e38f
#define NEGF -3.0e38f

// Accuracy (R9-R17, refines validated R6/R8 scheme): output = top-5 of per-
// (chunk x col-mod-16 class) bf16 acc maxima -- 1472 real candidate classes
// per row (92 non-empty chunks x 16). acc excludes the row-constant -x^2/2
// (cannot change per-row argmax); k_scan reconstructs d2 = x2 - 2*acc with
// fp32 x2. R17 is bit-identical to R16 (same candidate set, same MFMA/fmax
// order); only the sync schedule changes.

typedef __attribute__((ext_vector_type(8))) short short8;      // MFMA A/B frag (8 bf16)
typedef __attribute__((ext_vector_type(4))) unsigned short ushort4v;
typedef __attribute__((ext_vector_type(8))) unsigned short ushort8v;
typedef __attribute__((ext_vector_type(4))) float f32x4;       // 16x16 MFMA C/D frag

static __device__ __forceinline__ unsigned short f2bf(float f) {
  unsigned int u = __builtin_bit_cast(unsigned int, f);
  u = (u + 0x7FFFu + ((u >> 16) & 1u)) >> 16;   // RNE
  return (unsigned short)u;
}

static __device__ __forceinline__ void gload_lds16(const void* g, void* l) {
  __builtin_amdgcn_global_load_lds((const __attribute__((address_space(1))) unsigned int*)g,
                                   (__attribute__((address_space(3))) unsigned int*)l, 16, 0, 0);
}
static __device__ __forceinline__ void gload_lds4(const void* g, void* l) {
  __builtin_amdgcn_global_load_lds((const __attribute__((address_space(1))) unsigned int*)g,
                                   (__attribute__((address_space(3))) unsigned int*)l, 4, 0, 0);
}

#define DPPADD(v, ctrl)                                                              \
  do {                                                                               \
    int _t = __builtin_amdgcn_update_dpp(0, __builtin_bit_cast(int, (v)), (ctrl),    \
                                         0xf, 0xf, false);                           \
    (v) = (v) + __builtin_bit_cast(float, _t);                                       \
  } while (0)

// ---------------------------------------------------------------------------
// K0: bank fp32 -> bf16 slab-tiled + ny2 = -0.5*|y|^2 (pads NEGF).
// Lane-contiguous flat reads; LDS-staged tile; coalesced 16B/lane writes.
// Tiled layout: slab s, unit u = kc*64 + j holds Y[s*64+j][kc*8 .. kc*8+8).
// ---------------------------------------------------------------------------
__global__ __launch_bounds__(256) void k_prep(const float* __restrict__ Y,
                                              unsigned short* __restrict__ ybf,
                                              float* __restrict__ ny2) {
  const int s = blockIdx.x;
  const int t = threadIdx.x;
  __shared__ __align__(16) unsigned short tile[8192];   // 16 KB bf16 slab
  __shared__ float redy[64 * 33];                       // padded
#pragma unroll
  for (int i = 0; i < 8; ++i) {
    const int u = i * 256 + t;                  // flat float4 index in 32KB slab
    const int rowl = u >> 5;                    // 0..63
    const int q = u & 31;                       // float4 within row
    const int rowg = s * 64 + rowl;
    const int rowc = (rowg < M_B) ? rowg : (M_B - 1);
    const float4 v = ((const float4*)Y)[(size_t)rowc * 32 + q];
    redy[rowl * 33 + q] = v.x * v.x + v.y * v.y + v.z * v.z + v.w * v.w;
    ushort4v o;
    o[0] = f2bf(v.x); o[1] = f2bf(v.y); o[2] = f2bf(v.z); o[3] = f2bf(v.w);
    *(ushort4v*)(tile + (size_t)(((q >> 1) * 64 + rowl) * 8 + (q & 1) * 4)) = o;
  }
  __syncthreads();
  {
    const int rowl = t >> 2;                    // quad per row
    const int k = t & 3;
    float ss = 0.f;
#pragma unroll
    for (int j = 0; j < 8; ++j) ss += redy[rowl * 33 + k * 8 + j];
    DPPADD(ss, 0xB1);                           // quad xor1
    DPPADD(ss, 0x4E);                           // quad xor2 -> quad sum
    const int rowg = s * 64 + rowl;
    if ((t & 3) == 0) ny2[(size_t)s * 64 + rowl] = (rowg < M_B) ? (-0.5f * ss) : NEGF;
  }
#pragma unroll
  for (int i = 0; i < 4; ++i) {                 // coalesced 16B/lane global writes
    const int u = i * 256 + t;
    *(ushort8v*)(ybf + ((size_t)s * 1024 + u) * 8) = *(const ushort8v*)(tile + u * 8);
  }
}

// ---------------------------------------------------------------------------
// Main: block = 256 rows x one chunk, 4 waves x 64 rows, 16x16x32 bf16 MFMA,
// rt=4, ct-OUTER (R16 register plan, ~127 live regs, no spill).
// R17: SYNC RESTRUCTURE. R8 post-mortem: every clean config (8/12/16
// waves/CU, 16x16/32x32, rt=2/4) lands 50+-3us at MfmaUtil 37-45% -- the
// 2-barrier-per-slab lockstep is the binding constraint (m97-structure
// ceiling; m233: stage+vmcnt+barrier IS the critical path). Changes:
// (a) TRIPLE-buffered LDS -> ONE barrier per slab: stage for s+2 targets
//     the buffer slab s-1 used, freed by the barrier at slab s's start
//     (all waves crossed it only after finishing s-1's compute). The
//     end-of-slab WAR barrier is deleted (17 fewer rendezvous).
// (b) 2-slab-deep prefetch: stage s+2 (issued after iter s's barrier) has
//     slabs s AND s+1's compute to land; vmcnt(4) keeps 4 loads in flight,
//     vmcnt(0) only on the last slab.
// (c) T5 setprio(1) around each ct-pass's 16-MFMA cluster: single-barrier
//     drift creates wave role diversity -> scheduler has something to
//     arbitrate (m190's setprio null was the lockstep regime).
// LDS = 3x16384 + 4352 = 53504 B; 3 blocks x 53504 = 160.5KB <= 160KiB/CU
// -> still exactly 3 blk/CU. Grid 768; chunk = bid%96 (XCD-local).
// MFMA layouts (verified m89/m91): A[m=lane&15][k=(lane>>4)*8+j],
// B[n=lane&15][k=(lane>>4)*8+j], C/D col=lane&15 row=(lane>>4)*4+reg.
// ---------------------------------------------------------------------------
__global__ __launch_bounds__(256, 3) void k_main(const float* __restrict__ X,
                                                 const unsigned short* __restrict__ ybf,
                                                 const float* __restrict__ ny2,
                                                 float* __restrict__ rsm) {
  __shared__ __align__(16) char smem[53504];
  unsigned short* ys = (unsigned short*)smem;        // 49152: three 16KB slab bufs
  float* ny2s = (float*)(smem + 49152);              //  4352: whole chunk's ny2 (17x64)

  const int bid = blockIdx.x;
  const int chunk = bid % CHUNKS;                    // 0..95 (XCD-local)
  const int rowblock = bid / CHUNKS;                 // 0..7
  const int row0 = rowblock * TROWS;

  const int cs0 = chunk * SPC;
  int nslab = SLABS_TOTAL - cs0;                     // chunk 91: 16; chunks>=92: <=0
  if (nslab > SPC) nslab = SPC;
  if (nslab < 0) nslab = 0;

  const int t = threadIdx.x;
  const int wave = t >> 6;
  const int lane = t & 63;
  const int lm = lane & 15;
  const int lq = lane >> 4;                          // 0..3

  // ---- A fragments resident in registers (bf16): 64 rows per wave ----
  // afrag[rt][ks]: A[m=lm][k = lq*8 + j] for rowtile rt, k-step ks (K=32)
  short8 afrag[4][4];
#pragma unroll
  for (int rt = 0; rt < 4; ++rt)
#pragma unroll
    for (int ks = 0; ks < 4; ++ks) {
      const float* xr = X + (size_t)(row0 + wave * 64 + rt * 16 + lm) * D_DIM + ks * 32 + lq * 8;
      const float4 a = *(const float4*)xr;
      const float4 b = *(const float4*)(xr + 4);
      short8 f;
      f[0] = (short)f2bf(a.x); f[1] = (short)f2bf(a.y);
      f[2] = (short)f2bf(a.z); f[3] = (short)f2bf(a.w);
      f[4] = (short)f2bf(b.x); f[5] = (short)f2bf(b.y);
      f[6] = (short)f2bf(b.z); f[7] = (short)f2bf(b.w);
      afrag[rt][ks] = f;
    }

  // ---- one-time ny2 preload for the whole chunk (64 floats per slab) ----
  for (int j = wave; j < nslab; j += 4)
    gload_lds4(ny2 + (size_t)(cs0 + j) * 64 + lane, ny2s + (size_t)j * 64);
  __syncthreads();   // full drain: afrag loads + ny2 DMA; vmcnt==0 entering loop

  // persistent per-(row,class) running max: lane holds class lm, rows (rt,rr)
  float prmax[4][4];
#pragma unroll
  for (int rt = 0; rt < 4; ++rt)
#pragma unroll
    for (int rr = 0; rr < 4; ++rr) prmax[rt][rr] = NEGF;

  // ---- prologue: stage slab 0 -> buf0, slab 1 -> buf1 ----
#pragma unroll
  for (int p = 0; p < 2; ++p) {
    if (p < nslab) {
      const unsigned short* src = ybf + (size_t)(cs0 + p) * 8192;
      unsigned short* dst = ys + (size_t)p * 8192;
#pragma unroll
      for (int i = 0; i < 4; ++i) {
        const int ub = i * 256 + wave * 64;
        gload_lds16(src + (size_t)(ub + lane) * 8, dst + (size_t)ub * 8);
      }
    }
  }

  int cur = 0;                                       // buffer of slab s
  int prv = 2;                                       // buffer of slab s-1 == (s+2)%3
  for (int s = 0; s < nslab; ++s) {
    // wait for slab s's 4 loads; keep slab s+1's 4 (if any) in flight
    if (s + 1 < nslab) {
      asm volatile("s_waitcnt vmcnt(4)" ::: "memory");
    } else {
      asm volatile("s_waitcnt vmcnt(0)" ::: "memory");
    }
    __builtin_amdgcn_s_barrier();   // (a) slab-s DMA visible to all waves;
                                    // (b) all waves finished reading buf prv

    // stage slab s+2 into buf prv (freed by this barrier); lands during
    // slabs s and s+1's compute
    if (s + 2 < nslab) {
      const unsigned short* src = ybf + (size_t)(cs0 + s + 2) * 8192;
      unsigned short* dst = ys + (size_t)prv * 8192;
#pragma unroll
      for (int i = 0; i < 4; ++i) {
        const int ub = i * 256 + wave * 64;
        gload_lds16(src + (size_t)(ub + lane) * 8, dst + (size_t)ub * 8);
      }
    }

    const unsigned short* yb = ys + (size_t)cur * 8192;

    // ct-OUTER: one coltile at a time -> acc live-set is only 16 regs
#pragma unroll
    for (int ct = 0; ct < 4; ++ct) {
      const float yc = ny2s[s * 64 + ct * 16 + lm];  // -0.5*|y|^2, col ct*16+lm

      short8 bfr[4];
#pragma unroll
      for (int ks = 0; ks < 4; ++ks)
        bfr[ks] = *(const short8*)(yb + (size_t)(((ks * 4 + lq) * 64 + ct * 16 + lm)) * 8);

      f32x4 acc[4];                                  // [rowtile]
#pragma unroll
      for (int rt = 0; rt < 4; ++rt)
#pragma unroll
        for (int rr = 0; rr < 4; ++rr) acc[rt][rr] = yc;

      __builtin_amdgcn_s_setprio(1);
#pragma unroll
      for (int ks = 0; ks < 4; ++ks)
#pragma unroll
        for (int rt = 0; rt < 4; ++rt)
          acc[rt] = __builtin_amdgcn_mfma_f32_16x16x32_bf16(afrag[rt][ks], bfr[ks],
                                                            acc[rt], 0, 0, 0);
      __builtin_amdgcn_s_setprio(0);

#pragma unroll
      for (int rt = 0; rt < 4; ++rt)
#pragma unroll
        for (int rr = 0; rr < 4; ++rr)
          prmax[rt][rr] = fmaxf(prmax[rt][rr], acc[rt][rr]);
    }

    // rotate buffers: next slab's cur = cur+1; its prv = old cur's prv+1
    prv = cur;
    cur = (cur == 2) ? 0 : (cur + 1);
  }

  // ---- rsm write, row-major: rsm[row][chunk*CLS + lm], all 64 lanes ----
#pragma unroll
  for (int rt = 0; rt < 4; ++rt)
#pragma unroll
    for (int rr = 0; rr < 4; ++rr) {
      const int lrow = wave * 64 + rt * 16 + lq * 4 + rr;
      rsm[(size_t)(row0 + lrow) * FTOT + chunk * CLS + lm] = prmax[rt][rr];
    }
}

// ---------------------------------------------------------------------------
// K_scan: one wave per row. x2 = |x_row|^2 (fp32, wave reduce); top-5 largest
// acc over the row's 1536 class maxima (coalesced), per-lane sorted-5 + 5-round
// wave-max merge; d2 = x2 - 2*acc; sqrt/mean/normalize -> out[row].
// ---------------------------------------------------------------------------
__global__ __launch_bounds__(256) void k_scan(const float* __restrict__ rsm,
                                              const float* __restrict__ X,
                                              const float* __restrict__ minp,
                                              const float* __restrict__ maxp,
                                              float* __restrict__ out) {
  const int wave = threadIdx.x >> 6;
  const int lane = threadIdx.x & 63;
  const int row = blockIdx.x * 4 + wave;
  const float* rp = rsm + (size_t)row * FTOT;

  // x2: 2 floats per lane, butterfly sum
  float x2;
  {
    const float a = X[(size_t)row * D_DIM + lane];
    const float b = X[(size_t)row * D_DIM + 64 + lane];
    x2 = a * a + b * b;
#pragma unroll
    for (int off = 1; off < 64; off <<= 1) x2 += __shfl_xor(x2, off);
  }

  float t0 = NEGF, t1 = NEGF, t2 = NEGF, t3 = NEGF, t4 = NEGF;  // descending
  for (int i = lane; i < FTOT; i += 64) {
    const float v = rp[i];
    if (v > t4) {
      float m = v;
      float n3 = fminf(t3, m); m = fmaxf(t3, m);
      float n2 = fminf(t2, m); m = fmaxf(t2, m);
      float n1 = fminf(t1, m); m = fmaxf(t1, m);
      float n0 = fminf(t0, m); m = fmaxf(t0, m);
      t0 = m; t1 = n0; t2 = n1; t3 = n2; t4 = n3;
    }
  }

  int k = 0;
  float sum = 0.f;
#pragma unroll
  for (int r = 0; r < KNN; ++r) {
    float head = (k == 0) ? t0 : (k == 1) ? t1 : (k == 2) ? t2 : (k == 3) ? t3
               : (k == 4) ? t4 : NEGF;
    float m = head;
#pragma unroll
    for (int off = 1; off < 64; off <<= 1) m = fmaxf(m, __shfl_xor(m, off));
    const unsigned long long mask = __ballot(head == m);
    const int first = __ffsll(mask) - 1;
    if (lane == first) ++k;                      // consume exactly one holder
    sum += sqrtf(fmaxf(x2 - 2.f * m, 0.f));      // d = sqrt(x2 - 2*acc)
  }
  if (lane == 0) {
    const float mn = minp[0], mx = maxp[0];
    out[row] = (sum * (1.0f / KNN) - mn) / (mx - mn);
  }
}

extern "C" void kernel_launch(void* const* d_in, const int* in_sizes, int n_in,
                              void* d_out, int out_size, void* d_ws, size_t ws_size,
                              hipStream_t stream) {
  const float* X = (const float*)d_in[0];
  const float* Y = (const float*)d_in[1];
  const float* minp = (const float*)d_in[2];
  const float* maxp = (const float*)d_in[3];
  float* out = (float*)d_out;

  char* ws = (char*)d_ws;
  size_t off = 0;
  unsigned short* ybf = (unsigned short*)(ws + off); off += (size_t)M_PAD * D_DIM * 2;  // 25.6 MB
  float* ny2 = (float*)(ws + off);                   off += (size_t)M_PAD * 4;          // 400 KB
  float* rsm = (float*)(ws + off);                   off += (size_t)N_Q * FTOT * 4;     // 12.6 MB
  // total ~38.6 MB

  k_prep<<<dim3(SLABS_TOTAL), dim3(256), 0, stream>>>(Y, ybf, ny2);
  k_main<<<dim3(ROWBLOCKS * CHUNKS), dim3(256), 0, stream>>>(X, ybf, ny2, rsm);
  k_scan<<<dim3(N_Q / 4), dim3(256), 0, stream>>>(rsm, X, minp, maxp, out);
}